// Round 1
// baseline (94.714 us; speedup 1.0000x reference)
//
#include <hip/hip_runtime.h>

// Problem constants (B, N, D, H) from reference: (2, 1024, 128, 64)
#define Bb 2
#define Nn 1024
#define Dd 128
#define Hh 64
#define CHUNK 256              // j-chunk staged in LDS per step
#define NCHUNK (Nn / CHUNK)    // 4
#define IT 8                   // i-rows per block (2 per wave)

// ---------------------------------------------------------------------------
// Kernel 1: P[b][h][n] = sum_d E[b,n,d] * W1[h,d] + b1[h]
//           Q[b][h][n] = sum_d E[b,n,d] * W1[h,128+d]
// Transposed (h-major) output so the fused kernel can stage h-rows with
// coalesced 16B loads.  Grid: (4 o-tiles of 32, 16 n-tiles of 64, B).
// (unchanged from previous round — ~2 us, not the bottleneck)
// ---------------------------------------------------------------------------
__global__ __launch_bounds__(256)
void k1_proj(const float* __restrict__ E, const float* __restrict__ W1,
             const float* __restrict__ b1, float* __restrict__ Pt,
             float* __restrict__ Qt) {
  __shared__ float El[64 * 129];   // [n][d], stride 129 -> 2-way max
  __shared__ float Wl[128 * 33];   // [d][o], stride 33

  const int t = threadIdx.x;
  const int oBase = blockIdx.x * 32;
  const int nBase = blockIdx.y * 64;
  const int b = blockIdx.z;

  const float* esrc = E + ((size_t)b * Nn + nBase) * Dd;
  #pragma unroll
  for (int k = 0; k < 8; ++k) {
    int q = t + k * 256;
    int n = q >> 5;
    int c = (q & 31) << 2;
    float4 v = *(const float4*)(esrc + n * Dd + c);
    float* dst = &El[n * 129 + c];
    dst[0] = v.x; dst[1] = v.y; dst[2] = v.z; dst[3] = v.w;
  }
  #pragma unroll
  for (int k = 0; k < 16; ++k) {
    int q = t + k * 256;
    int o = q >> 7;         // 0..31 local
    int d = q & 127;
    int oG = oBase + o;
    int src = (oG < Hh) ? (oG * 2 * Dd + d) : ((oG - Hh) * 2 * Dd + Dd + d);
    Wl[d * 33 + o] = W1[src];
  }
  __syncthreads();

  const int tn = t & 15;   // n quad index
  const int to = t >> 4;   // o pair index (0..15)
  float acc[4][2] = {{0.f, 0.f}, {0.f, 0.f}, {0.f, 0.f}, {0.f, 0.f}};
  #pragma unroll 8
  for (int d = 0; d < 128; ++d) {
    float w0 = Wl[d * 33 + to * 2 + 0];
    float w1 = Wl[d * 33 + to * 2 + 1];
    #pragma unroll
    for (int a = 0; a < 4; ++a) {
      float e = El[(tn * 4 + a) * 129 + d];
      acc[a][0] = fmaf(e, w0, acc[a][0]);
      acc[a][1] = fmaf(e, w1, acc[a][1]);
    }
  }

  #pragma unroll
  for (int j = 0; j < 2; ++j) {
    int o = oBase + to * 2 + j;    // wave-uniform: blocks 0,1 -> P; 2,3 -> Q
    float4 v = make_float4(acc[0][j], acc[1][j], acc[2][j], acc[3][j]);
    float* dst;
    if (o < Hh) {
      float bias = b1[o];
      v.x += bias; v.y += bias; v.z += bias; v.w += bias;
      dst = Pt + ((size_t)b * Hh + o) * Nn + nBase + tn * 4;
    } else {
      dst = Qt + ((size_t)b * Hh + (o - Hh)) * Nn + nBase + tn * 4;
    }
    *(float4*)dst = v;
  }
}

// ---------------------------------------------------------------------------
// Fused kernel 2+3: edge[b,i,j] = b2 + sum_h w2[h]*relu(P[b,i,h]+Q[b,j,h]),
// then masked softmax over j — WITHOUT materializing the edge matrix.
//
// Block = 256 thr = 4 waves; block owns i-rows [iBase, iBase+8); wave ty owns
// rows 2ty, 2ty+1 COMPLETELY (64 lanes x 4 j x 4 chunks = 1024 j) so softmax
// max/sum are pure wave-internal __shfl_xor — no LDS reduce, no extra global
// round trip.  Q chunks (64 h x 256 j = 64 KB) are double-buffered in LDS via
// global_load_lds width=16: one wave-instruction stages one full 1 KB h-row
// (linear dest = wave-uniform row base + lane*16; per-lane src matches).
// LDS total = 128 KB (Ql) + 2 KB (Pl) -> 1 block/CU, grid = 256 = #CUs.
// Inner loop per h: 1 ds_read_b128 + 1 broadcast ds_read_b64 + 24 VALU
// -> VALU-bound (CU LDS pipe 40 cyc < 48 cyc VALU per SIMD per h-step).
// ---------------------------------------------------------------------------
__device__ __forceinline__ void gload_lds16(const float* g, float* l) {
  __builtin_amdgcn_global_load_lds(
      (const __attribute__((address_space(1))) void*)g,
      (__attribute__((address_space(3))) void*)l, 16, 0, 0);
}

__global__ __launch_bounds__(256)
void k23_fused(const float* __restrict__ Pt, const float* __restrict__ Qt,
               const float* __restrict__ W2, const float* __restrict__ b2,
               const int* __restrict__ visited, float* __restrict__ out) {
  __shared__ float Ql[2][Hh][CHUNK];   // 128 KB: double-buffered j-chunk, h-major
  __shared__ float Pl[Hh][IT];         // 2 KB: i-tile, h-major

  const int t  = threadIdx.x;
  const int tx = t & 63;               // lane id = j group (4 j per lane)
  const int ty = t >> 6;               // wave id -> owns rows 2ty, 2ty+1
  const int iBase = blockIdx.x * IT;
  const int b  = blockIdx.y;

  // Stage P tile: 64 h x 8 i (512 floats, L2-hot strided gather — trivial).
  #pragma unroll
  for (int k = 0; k < 2; ++k) {
    int e = t + k * 256;
    int h = e >> 3, i = e & 7;
    Pl[h][i] = Pt[((size_t)b * Hh + h) * Nn + iBase + i];
  }

  const float* qb = Qt + (size_t)b * Hh * Nn;

  // Async stage of j-chunk ch into buffer buf: each wave loads 16 h-rows.
  // Dest row base is wave-uniform (h depends only on ty); HW adds lane*16.
  auto stage = [&](int buf, int ch) {
    const int jB = ch * CHUNK;
    #pragma unroll
    for (int r = 0; r < 16; ++r) {
      const int h = ty * 16 + r;
      gload_lds16(qb + (size_t)h * Nn + jB + tx * 4, &Ql[buf][h][0]);
    }
  };

  float acc[2][16];                    // [row][ch*4 + c] — all indices static
  #pragma unroll
  for (int k = 0; k < 16; ++k) { acc[0][k] = 0.f; acc[1][k] = 0.f; }

  stage(0, 0);
  __syncthreads();                     // vmcnt(0)+barrier: chunk 0 resident

  #pragma unroll
  for (int ch = 0; ch < NCHUNK; ++ch) {
    const int buf = ch & 1;
    if (ch + 1 < NCHUNK) stage(buf ^ 1, ch + 1);  // prefetch hides under FMA

    #pragma unroll 8
    for (int h = 0; h < Hh; ++h) {
      const float  w = W2[h];          // uniform -> scalar load path
      const float4 q = *(const float4*)&Ql[buf][h][tx * 4];  // contiguous 1KB/row
      const float p0 = Pl[h][2 * ty + 0];                    // broadcast b64
      const float p1 = Pl[h][2 * ty + 1];
      const float qa[4] = {q.x, q.y, q.z, q.w};
      #pragma unroll
      for (int c = 0; c < 4; ++c) {
        acc[0][ch * 4 + c] = fmaf(w, fmaxf(p0 + qa[c], 0.f), acc[0][ch * 4 + c]);
        acc[1][ch * 4 + c] = fmaf(w, fmaxf(p1 + qa[c], 0.f), acc[1][ch * 4 + c]);
      }
    }
    __syncthreads();                   // drains our prefetch (vmcnt 0) + publish
  }

  // ---- masked softmax, fully in registers + wave shuffles ----
  const float NEG = -1000000000.0f;
  const float b2v = b2[0];
  const int vrow = b * Nn;
  const bool vi0 = visited[vrow + iBase + 2 * ty + 0] != 0;
  const bool vi1 = visited[vrow + iBase + 2 * ty + 1] != 0;

  float m0 = NEG, m1 = NEG;
  #pragma unroll
  for (int ch = 0; ch < NCHUNK; ++ch) {
    const int4 vj = *(const int4*)(visited + vrow + ch * CHUNK + tx * 4);
    const int vja[4] = {vj.x, vj.y, vj.z, vj.w};
    #pragma unroll
    for (int c = 0; c < 4; ++c) {
      const bool mj = vja[c] != 0;
      float v0 = (vi0 | mj) ? NEG : (acc[0][ch * 4 + c] + b2v);
      float v1 = (vi1 | mj) ? NEG : (acc[1][ch * 4 + c] + b2v);
      acc[0][ch * 4 + c] = v0;
      acc[1][ch * 4 + c] = v1;
      m0 = fmaxf(m0, v0);
      m1 = fmaxf(m1, v1);
    }
  }
  #pragma unroll
  for (int off = 32; off; off >>= 1) {
    m0 = fmaxf(m0, __shfl_xor(m0, off));
    m1 = fmaxf(m1, __shfl_xor(m1, off));
  }

  // All-masked row: every v=NEG -> m=NEG -> exp(0)=1, sum=N -> uniform 1/N,
  // matching the reference exactly.
  float s0 = 0.f, s1 = 0.f;
  #pragma unroll
  for (int k = 0; k < 16; ++k) {
    const float e0 = __expf(acc[0][k] - m0);
    const float e1 = __expf(acc[1][k] - m1);
    acc[0][k] = e0; acc[1][k] = e1;
    s0 += e0; s1 += e1;
  }
  #pragma unroll
  for (int off = 32; off; off >>= 1) {
    s0 += __shfl_xor(s0, off);
    s1 += __shfl_xor(s1, off);
  }
  const float i0 = 1.0f / s0, i1 = 1.0f / s1;

  float* o0 = out + (size_t)(b * Nn + iBase + 2 * ty + 0) * Nn;
  float* o1 = out + (size_t)(b * Nn + iBase + 2 * ty + 1) * Nn;
  #pragma unroll
  for (int ch = 0; ch < NCHUNK; ++ch) {
    const int j = ch * CHUNK + tx * 4;
    float4 w0 = make_float4(acc[0][ch * 4 + 0] * i0, acc[0][ch * 4 + 1] * i0,
                            acc[0][ch * 4 + 2] * i0, acc[0][ch * 4 + 3] * i0);
    float4 w1 = make_float4(acc[1][ch * 4 + 0] * i1, acc[1][ch * 4 + 1] * i1,
                            acc[1][ch * 4 + 2] * i1, acc[1][ch * 4 + 3] * i1);
    *(float4*)(o0 + j) = w0;
    *(float4*)(o1 + j) = w1;
  }
}

// ---------------------------------------------------------------------------
extern "C" void kernel_launch(void* const* d_in, const int* in_sizes, int n_in,
                              void* d_out, int out_size, void* d_ws, size_t ws_size,
                              hipStream_t stream) {
  const float* E       = (const float*)d_in[0];  // (B,N,D)
  const int*   visited = (const int*)d_in[1];    // (B,N) bool -> int32
  // d_in[2] remaining_capacity: unused by reference
  const float* W1      = (const float*)d_in[3];  // (H, 2D)
  const float* b1      = (const float*)d_in[4];  // (H,)
  const float* W2      = (const float*)d_in[5];  // (1, H)
  const float* b2      = (const float*)d_in[6];  // (1,)

  float* out = (float*)d_out;                    // (B,N,N)
  float* Pt  = (float*)d_ws;                     // B*H*N floats = 512 KB
  float* Qt  = (float*)((char*)d_ws + (size_t)Bb * Hh * Nn * sizeof(float));

  k1_proj<<<dim3(4, 16, Bb), 256, 0, stream>>>(E, W1, b1, Pt, Qt);
  k23_fused<<<dim3(Nn / IT, Bb), 256, 0, stream>>>(Pt, Qt, W2, b2, visited, out);
}

// Round 2
// 89.946 us; speedup vs baseline: 1.0530x; 1.0530x over previous
//
#include <hip/hip_runtime.h>

// Problem constants (B, N, D, H) from reference: (2, 1024, 128, 64)
#define Bb 2
#define Nn 1024
#define Dd 128
#define Hh 64

// ---------------------------------------------------------------------------
// Kernel 1: P[b][h][n] = sum_d E[b,n,d] * W1[h,d] + b1[h]
//           Q[b][h][n] = sum_d E[b,n,d] * W1[h,128+d]
// Transposed (h-major) output so the fused kernel reads h-rows coalesced.
// Grid: (4 o-tiles of 32, 16 n-tiles of 64, B).  ~2 us, unchanged.
// ---------------------------------------------------------------------------
__global__ __launch_bounds__(256)
void k1_proj(const float* __restrict__ E, const float* __restrict__ W1,
             const float* __restrict__ b1, float* __restrict__ Pt,
             float* __restrict__ Qt) {
  __shared__ float El[64 * 129];   // [n][d], stride 129 -> 2-way max
  __shared__ float Wl[128 * 33];   // [d][o], stride 33

  const int t = threadIdx.x;
  const int oBase = blockIdx.x * 32;
  const int nBase = blockIdx.y * 64;
  const int b = blockIdx.z;

  const float* esrc = E + ((size_t)b * Nn + nBase) * Dd;
  #pragma unroll
  for (int k = 0; k < 8; ++k) {
    int q = t + k * 256;
    int n = q >> 5;
    int c = (q & 31) << 2;
    float4 v = *(const float4*)(esrc + n * Dd + c);
    float* dst = &El[n * 129 + c];
    dst[0] = v.x; dst[1] = v.y; dst[2] = v.z; dst[3] = v.w;
  }
  #pragma unroll
  for (int k = 0; k < 16; ++k) {
    int q = t + k * 256;
    int o = q >> 7;         // 0..31 local
    int d = q & 127;
    int oG = oBase + o;
    int src = (oG < Hh) ? (oG * 2 * Dd + d) : ((oG - Hh) * 2 * Dd + Dd + d);
    Wl[d * 33 + o] = W1[src];
  }
  __syncthreads();

  const int tn = t & 15;   // n quad index
  const int to = t >> 4;   // o pair index (0..15)
  float acc[4][2] = {{0.f, 0.f}, {0.f, 0.f}, {0.f, 0.f}, {0.f, 0.f}};
  #pragma unroll 8
  for (int d = 0; d < 128; ++d) {
    float w0 = Wl[d * 33 + to * 2 + 0];
    float w1 = Wl[d * 33 + to * 2 + 1];
    #pragma unroll
    for (int a = 0; a < 4; ++a) {
      float e = El[(tn * 4 + a) * 129 + d];
      acc[a][0] = fmaf(e, w0, acc[a][0]);
      acc[a][1] = fmaf(e, w1, acc[a][1]);
    }
  }

  #pragma unroll
  for (int j = 0; j < 2; ++j) {
    int o = oBase + to * 2 + j;    // wave-uniform: blocks 0,1 -> P; 2,3 -> Q
    float4 v = make_float4(acc[0][j], acc[1][j], acc[2][j], acc[3][j]);
    float* dst;
    if (o < Hh) {
      float bias = b1[o];
      v.x += bias; v.y += bias; v.z += bias; v.w += bias;
      dst = Pt + ((size_t)b * Hh + o) * Nn + nBase + tn * 4;
    } else {
      dst = Qt + ((size_t)b * Hh + (o - Hh)) * Nn + nBase + tn * 4;
    }
    *(float4*)dst = v;
  }
}

// ---------------------------------------------------------------------------
// Fused kernel 2+3 (v2): edge -> masked softmax, no intermediate matrix.
//
// Occupancy-first restructure vs v1 (which was 1 wave/SIMD, LDS-staging
// bound):
//   - NO LDS staging of Q: Q is 256 KB/batch = L2-resident.  Each wave
//     amortizes its Q reads over 4 i-rows, so total Q traffic is
//     2048 waves x 64 KB = 134 MB from L2 (~4 us at L2 BW) < VALU floor.
//   - block = 512 thr = 8 waves; block owns 4 i-rows; wave wv covers the
//     128-j slice [wv*128, wv*128+128) for all 4 rows (2 j per lane).
//     Grid = 512 blocks = 2 blocks/CU -> 16 waves/CU = 4 waves/SIMD.
//   - P tile (64h x 4 rows = 1 KB LDS) read via broadcast ds_read_b128.
//   - q double-buffered in registers (load h+1 while computing h).
//   - Per h per lane: 24 VALU + 1 global float2 + 1 LDS b128 -> VALU-bound.
//   - Softmax: lane-local + 6-step __shfl_xor per wave, then one tiny
//     cross-wave LDS reduce (8 partials/row).  Two barriers total.
// ---------------------------------------------------------------------------
__global__ __launch_bounds__(512)
void k23_fused(const float* __restrict__ Pt, const float* __restrict__ Qt,
               const float* __restrict__ W2, const float* __restrict__ b2,
               const int* __restrict__ visited, float* __restrict__ out) {
  __shared__ float Pl[Hh][4];     // [h][r]  1 KB
  __shared__ float Ml[4][8];      // [row][wave] partial max
  __shared__ float Sl[4][8];      // [row][wave] partial sum

  const int t    = threadIdx.x;
  const int lane = t & 63;
  const int wv   = t >> 6;          // wave id = j-slice (0..7)
  const int iBase = blockIdx.x * 4;
  const int b    = blockIdx.y;

  // Stage P: 64 h x 4 rows, one element per thread (L2-hot strided gather).
  if (t < 256) {
    const int h = t >> 2, r = t & 3;
    Pl[h][r] = Pt[((size_t)b * Hh + h) * Nn + iBase + r];
  }
  __syncthreads();

  const int jOff = wv * 128 + lane * 2;
  const float* qcol = Qt + (size_t)b * Hh * Nn + jOff;

  float acc[4][2];
  #pragma unroll
  for (int r = 0; r < 4; ++r) { acc[r][0] = 0.f; acc[r][1] = 0.f; }

  float2 qn = *(const float2*)qcol;              // prefetch h=0
  #pragma unroll 8
  for (int h = 0; h < Hh; ++h) {
    const float2 q = qn;
    if (h + 1 < Hh) qn = *(const float2*)(qcol + (size_t)(h + 1) * Nn);
    const float w = W2[h];                       // uniform -> scalar load
    const float4 p4 = *(const float4*)&Pl[h][0]; // broadcast b128
    const float p[4] = {p4.x, p4.y, p4.z, p4.w};
    const float qa[2] = {q.x, q.y};
    #pragma unroll
    for (int r = 0; r < 4; ++r) {
      acc[r][0] = fmaf(w, fmaxf(p[r] + qa[0], 0.f), acc[r][0]);
      acc[r][1] = fmaf(w, fmaxf(p[r] + qa[1], 0.f), acc[r][1]);
    }
  }

  // ---- masked softmax ----
  const float NEG = -1000000000.0f;
  const float b2v = b2[0];
  const int vrow = b * Nn;

  bool vi[4];
  #pragma unroll
  for (int r = 0; r < 4; ++r) vi[r] = visited[vrow + iBase + r] != 0;

  const int2 vj = *(const int2*)(visited + vrow + jOff);
  const bool mj0 = vj.x != 0, mj1 = vj.y != 0;

  float vv[4][2];
  float m[4];
  #pragma unroll
  for (int r = 0; r < 4; ++r) {
    float x0 = (vi[r] | mj0) ? NEG : acc[r][0] + b2v;
    float x1 = (vi[r] | mj1) ? NEG : acc[r][1] + b2v;
    vv[r][0] = x0; vv[r][1] = x1;
    m[r] = fmaxf(x0, x1);
  }
  #pragma unroll
  for (int off = 32; off; off >>= 1)
    #pragma unroll
    for (int r = 0; r < 4; ++r)
      m[r] = fmaxf(m[r], __shfl_xor(m[r], off));
  if (lane == 0) {
    #pragma unroll
    for (int r = 0; r < 4; ++r) Ml[r][wv] = m[r];
  }
  __syncthreads();
  #pragma unroll
  for (int r = 0; r < 4; ++r) {
    const float4 a = *(const float4*)&Ml[r][0];
    const float4 c = *(const float4*)&Ml[r][4];
    m[r] = fmaxf(fmaxf(fmaxf(a.x, a.y), fmaxf(a.z, a.w)),
                 fmaxf(fmaxf(c.x, c.y), fmaxf(c.z, c.w)));
  }

  // All-masked row: every vv=NEG -> m=NEG -> exp(0)=1, sum=N -> uniform 1/N,
  // matching the reference exactly.
  float e[4][2];
  float s[4];
  #pragma unroll
  for (int r = 0; r < 4; ++r) {
    e[r][0] = __expf(vv[r][0] - m[r]);
    e[r][1] = __expf(vv[r][1] - m[r]);
    s[r] = e[r][0] + e[r][1];
  }
  #pragma unroll
  for (int off = 32; off; off >>= 1)
    #pragma unroll
    for (int r = 0; r < 4; ++r)
      s[r] += __shfl_xor(s[r], off);
  if (lane == 0) {
    #pragma unroll
    for (int r = 0; r < 4; ++r) Sl[r][wv] = s[r];
  }
  __syncthreads();
  #pragma unroll
  for (int r = 0; r < 4; ++r) {
    const float4 a = *(const float4*)&Sl[r][0];
    const float4 c = *(const float4*)&Sl[r][4];
    s[r] = ((a.x + a.y) + (a.z + a.w)) + ((c.x + c.y) + (c.z + c.w));
  }

  #pragma unroll
  for (int r = 0; r < 4; ++r) {
    const float inv = 1.0f / s[r];
    float* orow = out + ((size_t)(b * Nn + iBase + r)) * Nn + jOff;
    float2 vout = make_float2(e[r][0] * inv, e[r][1] * inv);
    *(float2*)orow = vout;
  }
}

// ---------------------------------------------------------------------------
extern "C" void kernel_launch(void* const* d_in, const int* in_sizes, int n_in,
                              void* d_out, int out_size, void* d_ws, size_t ws_size,
                              hipStream_t stream) {
  const float* E       = (const float*)d_in[0];  // (B,N,D)
  const int*   visited = (const int*)d_in[1];    // (B,N) bool -> int32
  // d_in[2] remaining_capacity: unused by reference
  const float* W1      = (const float*)d_in[3];  // (H, 2D)
  const float* b1      = (const float*)d_in[4];  // (H,)
  const float* W2      = (const float*)d_in[5];  // (1, H)
  const float* b2      = (const float*)d_in[6];  // (1,)

  float* out = (float*)d_out;                    // (B,N,N)
  float* Pt  = (float*)d_ws;                     // B*H*N floats = 512 KB
  float* Qt  = (float*)((char*)d_ws + (size_t)Bb * Hh * Nn * sizeof(float));

  k1_proj<<<dim3(4, 16, Bb), 256, 0, stream>>>(E, W1, b1, Pt, Qt);
  k23_fused<<<dim3(Nn / 4, Bb), 512, 0, stream>>>(Pt, Qt, W2, b2, visited, out);
}

// Round 3
// 86.579 us; speedup vs baseline: 1.0940x; 1.0389x over previous
//
#include <hip/hip_runtime.h>

// Problem constants (B, N, D, H) from reference: (2, 1024, 128, 64)
#define Bb 2
#define Nn 1024
#define Dd 128
#define Hh 64

// ---------------------------------------------------------------------------
// Kernel 1 (v2): P[b][h][n] = sum_d E[b,n,d]*W1[h,d] + b1[h]
//                Q[b][h][n] = sum_d E[b,n,d]*W1[h,128+d]
// vs v1: tile 32o x 32n, grid (4,32,B) = 256 blocks -> ALL 256 CUs busy
// (v1 used 128).  Per-thread micro-tile = 4 consecutive o x 1 n:
//   per d: 1 broadcast ds_read_b32 (E) + 1 ds_read_b128 (W) + 4 FMA
//   = 6 instr/d vs 14 in v1.
// Layouts: El[n][132] -> staging is conflict-free ds_write_b128, compute
// reads 8 distinct banks (4n+d).  Wl[d][36] -> b128 read granules to4=0..7
// cover all 32 banks (conflict-free); the 8-way conflict on Wl *writes* is
// a one-time staging cost (~45 cyc).
// ---------------------------------------------------------------------------
__global__ __launch_bounds__(256)
void k1_proj(const float* __restrict__ E, const float* __restrict__ W1,
             const float* __restrict__ b1, float* __restrict__ Pt,
             float* __restrict__ Qt) {
  __shared__ float El[32 * 132];   // [n][d], stride 132 (16B-aligned rows)
  __shared__ float Wl[128 * 36];   // [d][o], stride 36 (16B-aligned rows)

  const int t = threadIdx.x;
  const int oBase = blockIdx.x * 32;   // blocks 0,1 -> P rows; 2,3 -> Q rows
  const int nBase = blockIdx.y * 32;
  const int b = blockIdx.z;

  // Stage E tile (32 n x 128 d): coalesced float4 reads, b128 LDS writes.
  const float* esrc = E + ((size_t)b * Nn + nBase) * Dd;
  #pragma unroll
  for (int k = 0; k < 4; ++k) {
    int q = t + k * 256;
    int n = q >> 5;
    int c = (q & 31) << 2;
    float4 v = *(const float4*)(esrc + n * Dd + c);
    *(float4*)&El[n * 132 + c] = v;
  }
  // Stage W tile transposed: Wl[d][o].  Coalesced global rows of W1.
  #pragma unroll
  for (int k = 0; k < 16; ++k) {
    int q = t + k * 256;
    int o = q >> 7;         // 0..31 local
    int d = q & 127;
    int oG = oBase + o;
    int src = (oG < Hh) ? (oG * 2 * Dd + d) : ((oG - Hh) * 2 * Dd + Dd + d);
    Wl[d * 36 + o] = W1[src];
  }
  __syncthreads();

  const int to4 = (t & 7) << 2;   // o quad base (0,4,..,28)
  const int n   = t >> 3;         // node 0..31
  float a0 = 0.f, a1 = 0.f, a2 = 0.f, a3 = 0.f;
  #pragma unroll 8
  for (int d = 0; d < 128; ++d) {
    const float  e  = El[n * 132 + d];            // 8-addr broadcast read
    const float4 w4 = *(const float4*)&Wl[d * 36 + to4];
    a0 = fmaf(e, w4.x, a0);
    a1 = fmaf(e, w4.y, a1);
    a2 = fmaf(e, w4.z, a2);
    a3 = fmaf(e, w4.w, a3);
  }

  const int oG = oBase + to4;     // wave-uniform P/Q side
  if (oG < Hh) {
    const float4 bias = *(const float4*)&b1[oG];
    float* dst = Pt + ((size_t)b * Hh + oG) * Nn + nBase + n;
    dst[0 * Nn] = a0 + bias.x;
    dst[1 * Nn] = a1 + bias.y;
    dst[2 * Nn] = a2 + bias.z;
    dst[3 * Nn] = a3 + bias.w;
  } else {
    float* dst = Qt + ((size_t)b * Hh + (oG - Hh)) * Nn + nBase + n;
    dst[0 * Nn] = a0;
    dst[1 * Nn] = a1;
    dst[2 * Nn] = a2;
    dst[3 * Nn] = a3;
  }
}

// ---------------------------------------------------------------------------
// Fused kernel 2+3 (v3): edge -> masked softmax, no intermediate matrix.
// Structure as round 2 (4 i-rows/block, 8 waves x 128-j slices, 2 blocks/CU
// = 4 waves/SIMD, Q direct from L2, softmax in registers + shuffles).
// v3 deltas:
//   - q loads addressed as (uniform row base) + (per-lane jOff) so the
//     compiler can emit global_load_dwordx2 v,voff,s[base] with SALU base
//     stepping (off the VALU pipe).
//   - 2-deep register prefetch (L2 latency ~200cyc vs ~100-190cyc/h of
//     VALU issue at 4 waves/SIMD); branch-free: h=64,65 over-read lands
//     8 KB past Qt inside the 256 MiB workspace (values dead).
// ---------------------------------------------------------------------------
__global__ __launch_bounds__(512)
void k23_fused(const float* __restrict__ Pt, const float* __restrict__ Qt,
               const float* __restrict__ W2, const float* __restrict__ b2,
               const int* __restrict__ visited, float* __restrict__ out) {
  __shared__ float Pl[Hh][4];     // [h][r]  1 KB
  __shared__ float Ml[4][8];      // [row][wave] partial max
  __shared__ float Sl[4][8];      // [row][wave] partial sum

  const int t    = threadIdx.x;
  const int lane = t & 63;
  const int wv   = t >> 6;          // wave id = j-slice (0..7)
  const int iBase = blockIdx.x * 4;
  const int b    = blockIdx.y;

  // Stage P: 64 h x 4 rows (L2-hot strided gather, one element/thread).
  if (t < 256) {
    const int h = t >> 2, r = t & 3;
    Pl[h][r] = Pt[((size_t)b * Hh + h) * Nn + iBase + r];
  }
  __syncthreads();

  const int jOff = wv * 128 + lane * 2;
  const float* qbase = Qt + (size_t)b * Hh * Nn;   // wave-uniform base

  float acc[4][2];
  #pragma unroll
  for (int r = 0; r < 4; ++r) { acc[r][0] = 0.f; acc[r][1] = 0.f; }

  // 2-deep register prefetch pipeline.
  float2 q0 = *(const float2*)(qbase + 0 * Nn + jOff);
  float2 q1 = *(const float2*)(qbase + 1 * Nn + jOff);
  #pragma unroll 8
  for (int h = 0; h < Hh; ++h) {
    const float2 q = (h & 1) ? q1 : q0;
    const float* qnext = qbase + (size_t)(h + 2) * Nn;  // uniform row base
    if (h & 1) q1 = *(const float2*)(qnext + jOff);     // h&1 static (unroll 8)
    else       q0 = *(const float2*)(qnext + jOff);

    const float  w  = W2[h];                       // uniform -> s_load
    const float4 p4 = *(const float4*)&Pl[h][0];   // single-addr broadcast
    const float p[4] = {p4.x, p4.y, p4.z, p4.w};
    const float qa[2] = {q.x, q.y};
    #pragma unroll
    for (int r = 0; r < 4; ++r) {
      acc[r][0] = fmaf(w, fmaxf(p[r] + qa[0], 0.f), acc[r][0]);
      acc[r][1] = fmaf(w, fmaxf(p[r] + qa[1], 0.f), acc[r][1]);
    }
  }

  // ---- masked softmax (per-row: lane-local -> wave shuffle -> 8-way LDS) --
  const float NEG = -1000000000.0f;
  const float b2v = b2[0];
  const int vrow = b * Nn;

  bool vi[4];
  #pragma unroll
  for (int r = 0; r < 4; ++r) vi[r] = visited[vrow + iBase + r] != 0;

  const int2 vj = *(const int2*)(visited + vrow + jOff);
  const bool mj0 = vj.x != 0, mj1 = vj.y != 0;

  float vv[4][2];
  float m[4];
  #pragma unroll
  for (int r = 0; r < 4; ++r) {
    float x0 = (vi[r] | mj0) ? NEG : acc[r][0] + b2v;
    float x1 = (vi[r] | mj1) ? NEG : acc[r][1] + b2v;
    vv[r][0] = x0; vv[r][1] = x1;
    m[r] = fmaxf(x0, x1);
  }
  #pragma unroll
  for (int off = 32; off; off >>= 1)
    #pragma unroll
    for (int r = 0; r < 4; ++r)
      m[r] = fmaxf(m[r], __shfl_xor(m[r], off));
  if (lane == 0) {
    #pragma unroll
    for (int r = 0; r < 4; ++r) Ml[r][wv] = m[r];
  }
  __syncthreads();
  #pragma unroll
  for (int r = 0; r < 4; ++r) {
    const float4 a = *(const float4*)&Ml[r][0];
    const float4 c = *(const float4*)&Ml[r][4];
    m[r] = fmaxf(fmaxf(fmaxf(a.x, a.y), fmaxf(a.z, a.w)),
                 fmaxf(fmaxf(c.x, c.y), fmaxf(c.z, c.w)));
  }

  // All-masked row: every vv=NEG -> m=NEG -> exp(0)=1, sum=N -> uniform 1/N,
  // matching the reference exactly.
  float e[4][2];
  float s[4];
  #pragma unroll
  for (int r = 0; r < 4; ++r) {
    e[r][0] = __expf(vv[r][0] - m[r]);
    e[r][1] = __expf(vv[r][1] - m[r]);
    s[r] = e[r][0] + e[r][1];
  }
  #pragma unroll
  for (int off = 32; off; off >>= 1)
    #pragma unroll
    for (int r = 0; r < 4; ++r)
      s[r] += __shfl_xor(s[r], off);
  if (lane == 0) {
    #pragma unroll
    for (int r = 0; r < 4; ++r) Sl[r][wv] = s[r];
  }
  __syncthreads();
  #pragma unroll
  for (int r = 0; r < 4; ++r) {
    const float4 a = *(const float4*)&Sl[r][0];
    const float4 c = *(const float4*)&Sl[r][4];
    s[r] = ((a.x + a.y) + (a.z + a.w)) + ((c.x + c.y) + (c.z + c.w));
  }

  #pragma unroll
  for (int r = 0; r < 4; ++r) {
    const float inv = 1.0f / s[r];
    float* orow = out + ((size_t)(b * Nn + iBase + r)) * Nn + jOff;
    *(float2*)orow = make_float2(e[r][0] * inv, e[r][1] * inv);
  }
}

// ---------------------------------------------------------------------------
extern "C" void kernel_launch(void* const* d_in, const int* in_sizes, int n_in,
                              void* d_out, int out_size, void* d_ws, size_t ws_size,
                              hipStream_t stream) {
  const float* E       = (const float*)d_in[0];  // (B,N,D)
  const int*   visited = (const int*)d_in[1];    // (B,N) bool -> int32
  // d_in[2] remaining_capacity: unused by reference
  const float* W1      = (const float*)d_in[3];  // (H, 2D)
  const float* b1      = (const float*)d_in[4];  // (H,)
  const float* W2      = (const float*)d_in[5];  // (1, H)
  const float* b2      = (const float*)d_in[6];  // (1,)

  float* out = (float*)d_out;                    // (B,N,N)
  float* Pt  = (float*)d_ws;                     // B*H*N floats = 512 KB
  float* Qt  = (float*)((char*)d_ws + (size_t)Bb * Hh * Nn * sizeof(float));

  k1_proj<<<dim3(4, 32, Bb), 256, 0, stream>>>(E, W1, b1, Pt, Qt);
  k23_fused<<<dim3(Nn / 4, Bb), 512, 0, stream>>>(Pt, Qt, W2, b2, visited, out);
}